// Round 1
// baseline (86.213 us; speedup 1.0000x reference)
//
#include <hip/hip_runtime.h>
#include <math.h>

// Triangle-triangle intersection (Moller-style, matching the JAX reference
// bit-for-bit where it matters):
//  - EPS snap of near-plane distances at 1e-6
//  - interval test on the dominant axis of the plane-plane intersection line
//  - fp contract OFF in the geometric core so GPU f32 mul/add match the CPU
//    reference's separately-rounded ops (the snap threshold sits inside the
//    cancellation noise of the distance dot products).

static constexpr float EPS_SNAP = 1e-6f;

__device__ __forceinline__ float snapz(float x) {
    return (fabsf(x) < EPS_SNAP) ? 0.0f : x;
}

// Interval of the intersection line covered by one triangle.
// p[3]: projections of the 3 verts on the dominant axis; d[3]: snapped signed
// distances to the other triangle's plane. Empty -> (+inf, -inf).
__device__ __forceinline__ void tri_interval(const float p[3], const float d[3],
                                             float& tmin, float& tmax) {
#pragma clang fp contract(off)
    tmin = INFINITY;
    tmax = -INFINITY;
#pragma unroll
    for (int e = 0; e < 3; ++e) {
        const int i0 = e;
        const int i1 = (e + 1) % 3;  // nxt = [1,2,0] -> edges (0,1),(1,2),(2,0)
        const float di = d[i0], dj = d[i1];
        const float pi = p[i0], pj = p[i1];
        const bool valid = (di * dj <= 0.0f) && !((di == 0.0f) && (dj == 0.0f));
        const float denom = di - dj;
        const float dsafe = (denom == 0.0f) ? 1.0f : denom;
        // reference order: pi + ((pj - pi) * di) / denom
        const float t = pi + ((pj - pi) * di) / dsafe;
        if (valid) {
            tmin = fminf(tmin, t);
            tmax = fmaxf(tmax, t);
        }
    }
}

// Block tile: 64 cols x 4 rows -> 256 threads, 68 unique triangles per block
// (2.4 KB), fully cache-resident. Writes are 64 contiguous floats per wave.
__global__ __launch_bounds__(256) void tri_pairs_kernel(
    const float* __restrict__ tri, float* __restrict__ out, int n)
{
#pragma clang fp contract(off)
    const int j = blockIdx.x * 64 + threadIdx.x;  // column (triangle u)
    const int i = blockIdx.y * 4 + threadIdx.y;   // row    (triangle b)
    if (i >= n || j >= n) return;

    const float* __restrict__ A = tri + (size_t)i * 9;
    const float* __restrict__ B = tri + (size_t)j * 9;

    float Av[9], Bv[9];
#pragma unroll
    for (int k = 0; k < 9; ++k) { Av[k] = A[k]; Bv[k] = B[k]; }

    // Plane of A: n_a = cross(A1-A0, A2-A0), d_a = -dot(n_a, A0)
    const float ae1x = Av[3] - Av[0], ae1y = Av[4] - Av[1], ae1z = Av[5] - Av[2];
    const float ae2x = Av[6] - Av[0], ae2y = Av[7] - Av[1], ae2z = Av[8] - Av[2];
    const float nax = ae1y * ae2z - ae1z * ae2y;
    const float nay = ae1z * ae2x - ae1x * ae2z;
    const float naz = ae1x * ae2y - ae1y * ae2x;
    const float da = -(((nax * Av[0]) + (nay * Av[1])) + (naz * Av[2]));

    // Plane of B
    const float be1x = Bv[3] - Bv[0], be1y = Bv[4] - Bv[1], be1z = Bv[5] - Bv[2];
    const float be2x = Bv[6] - Bv[0], be2y = Bv[7] - Bv[1], be2z = Bv[8] - Bv[2];
    const float nbx = be1y * be2z - be1z * be2y;
    const float nby = be1z * be2x - be1x * be2z;
    const float nbz = be1x * be2y - be1y * be2x;
    const float db = -(((nbx * Bv[0]) + (nby * Bv[1])) + (nbz * Bv[2]));

    // Signed distances: A's verts vs plane B (dv), B's verts vs plane A (du),
    // left-to-right 3-term dot then +offset, then EPS snap (reference order).
    float dv[3], du[3];
#pragma unroll
    for (int v = 0; v < 3; ++v) {
        dv[v] = snapz((((Av[3 * v] * nbx) + (Av[3 * v + 1] * nby)) + (Av[3 * v + 2] * nbz)) + db);
        du[v] = snapz((((Bv[3 * v] * nax) + (Bv[3 * v + 1] * nay)) + (Bv[3 * v + 2] * naz)) + da);
    }

    const bool ssv = (dv[0] > 0.0f && dv[1] > 0.0f && dv[2] > 0.0f) ||
                     (dv[0] < 0.0f && dv[1] < 0.0f && dv[2] < 0.0f);
    const bool ssu = (du[0] > 0.0f && du[1] > 0.0f && du[2] > 0.0f) ||
                     (du[0] < 0.0f && du[1] < 0.0f && du[2] < 0.0f);

    // Direction of the plane-plane intersection line: D = cross(n_a, n_b)
    const float Dx = nay * nbz - naz * nby;
    const float Dy = naz * nbx - nax * nbz;
    const float Dz = nax * nby - nay * nbx;
    const float m0 = fabsf(Dx), m1 = fabsf(Dy), m2 = fabsf(Dz);
    // argmax, first occurrence on ties (numpy semantics)
    int axm = 0;
    float mm = m0;
    if (m1 > mm) { axm = 1; mm = m1; }
    if (m2 > mm) { axm = 2; }

    // Project verts on the dominant axis (explicit selects, no scratch array)
    float pv[3], pu[3];
#pragma unroll
    for (int v = 0; v < 3; ++v) {
        const float a0 = Av[3 * v], a1 = Av[3 * v + 1], a2 = Av[3 * v + 2];
        const float b0 = Bv[3 * v], b1 = Bv[3 * v + 1], b2 = Bv[3 * v + 2];
        pv[v] = (axm == 0) ? a0 : ((axm == 1) ? a1 : a2);
        pu[v] = (axm == 0) ? b0 : ((axm == 1) ? b1 : b2);
    }

    float t0v, t1v, t0u, t1u;
    tri_interval(pv, dv, t0v, t1v);
    tri_interval(pu, du, t0u, t1u);

    const bool overlap = fmaxf(t0v, t0u) <= fminf(t1v, t1u);
    const bool hit = (!ssv) && (!ssu) && overlap;

    float r = hit ? 1.0f : 0.0f;
    if (i == j) r = 1.0f;  // reference adds identity
    out[(size_t)i * n + j] = r;
}

extern "C" void kernel_launch(void* const* d_in, const int* in_sizes, int n_in,
                              void* d_out, int out_size, void* d_ws, size_t ws_size,
                              hipStream_t stream) {
    const float* tri = (const float*)d_in[0];
    float* out = (float*)d_out;
    const int n = in_sizes[0] / 9;  // 2048

    dim3 block(64, 4);
    dim3 grid((n + 63) / 64, (n + 3) / 4);
    tri_pairs_kernel<<<grid, block, 0, stream>>>(tri, out, n);
}

// Round 2
// 78.635 us; speedup vs baseline: 1.0964x; 1.0964x over previous
//
#include <hip/hip_runtime.h>
#include <math.h>

// Triangle-triangle intersection, bit-exact vs the numpy/JAX reference:
//  - EPS snap of near-plane distances at 1e-6, reference op order, fp
//    contract OFF (snap threshold sits inside dot-product cancellation noise).
//  - M is bitwise symmetric under pair swap (role swap negates D=cross(na,nb)
//    but |D| and both triangle intervals are unchanged), and the reference
//    only computes triu and mirrors -> we compute only tiles with tr<=tc and
//    write both orientations.
//  - Per-triangle plane (normal, offset) precomputed once in d_ws.

static constexpr float EPS_SNAP = 1e-6f;
static constexpr int TS = 32;  // tile size (square), n assumed divisible (n=2048)

__device__ __forceinline__ float snapz(float x) {
    return (fabsf(x) < EPS_SNAP) ? 0.0f : x;
}

// Interval of the intersection line covered by one triangle (reference order).
__device__ __forceinline__ void tri_interval(const float p[3], const float d[3],
                                             float& tmin, float& tmax) {
#pragma clang fp contract(off)
    tmin = INFINITY;
    tmax = -INFINITY;
#pragma unroll
    for (int e = 0; e < 3; ++e) {
        const int i0 = e;
        const int i1 = (e + 1) % 3;  // edges (0,1),(1,2),(2,0)
        const float di = d[i0], dj = d[i1];
        const float pi = p[i0], pj = p[i1];
        const bool valid = (di * dj <= 0.0f) && !((di == 0.0f) && (dj == 0.0f));
        const float denom = di - dj;
        const float dsafe = (denom == 0.0f) ? 1.0f : denom;
        const float t = pi + ((pj - pi) * di) / dsafe;  // ((pj-pi)*di)/denom
        if (valid) {
            tmin = fminf(tmin, t);
            tmax = fmaxf(tmax, t);
        }
    }
}

// Pre-pass: per-triangle plane normal + offset, same arithmetic order as ref.
__global__ __launch_bounds__(256) void plane_kernel(
    const float* __restrict__ tri, float4* __restrict__ planes, int n)
{
#pragma clang fp contract(off)
    const int i = blockIdx.x * 256 + threadIdx.x;
    if (i >= n) return;
    const float* A = tri + (size_t)i * 9;
    float Av[9];
#pragma unroll
    for (int k = 0; k < 9; ++k) Av[k] = A[k];
    const float e1x = Av[3] - Av[0], e1y = Av[4] - Av[1], e1z = Av[5] - Av[2];
    const float e2x = Av[6] - Av[0], e2y = Av[7] - Av[1], e2z = Av[8] - Av[2];
    const float nx = e1y * e2z - e1z * e2y;
    const float ny = e1z * e2x - e1x * e2z;
    const float nz = e1x * e2y - e1y * e2x;
    const float d = -(((nx * Av[0]) + (ny * Av[1])) + (nz * Av[2]));
    planes[i] = make_float4(nx, ny, nz, d);
}

// Main: 32x32 upper-triangular tiles. blockDim (32,8); each thread holds one
// column-triangle in registers and sweeps 4 rows (row data broadcast from LDS).
__global__ __launch_bounds__(256) void tile_kernel(
    const float* __restrict__ tri, const float4* __restrict__ planes,
    float* __restrict__ out, int n)
{
#pragma clang fp contract(off)
    const int tc = blockIdx.x, tr = blockIdx.y;
    if (tr > tc) return;  // uniform per block; mirror handled by upper tile
    const int C = tc * TS, R = tr * TS;

    __shared__ float As[TS][13];          // 9 verts + normal(3) + offset(1)
    __shared__ float Sres[TS][TS + 1];    // result tile, padded

    const int tx = threadIdx.x;                  // 0..31 (column in tile)
    const int t = threadIdx.y * 32 + tx;         // 0..255

    // Stage row triangles + their planes into LDS.
    if (t < TS) {
        const float* a = tri + (size_t)(R + t) * 9;
#pragma unroll
        for (int k = 0; k < 9; ++k) As[t][k] = a[k];
        const float4 p = planes[R + t];
        As[t][9] = p.x; As[t][10] = p.y; As[t][11] = p.z; As[t][12] = p.w;
    }

    // Column triangle in registers (reused for 4 rows).
    const int j = C + tx;
    const float* b = tri + (size_t)j * 9;
    float Bv[9];
#pragma unroll
    for (int k = 0; k < 9; ++k) Bv[k] = b[k];
    const float4 pb = planes[j];
    const float nbx = pb.x, nby = pb.y, nbz = pb.z, db = pb.w;

    __syncthreads();

#pragma unroll
    for (int kk = 0; kk < 4; ++kk) {
        const int r = threadIdx.y + 8 * kk;  // 0..31
        const int i = R + r;

        float Av[9];
#pragma unroll
        for (int k = 0; k < 9; ++k) Av[k] = As[r][k];
        const float nax = As[r][9], nay = As[r][10], naz = As[r][11], da = As[r][12];

        // Signed distances (left-to-right 3-term dot + offset, then snap).
        float dv[3], du[3];
#pragma unroll
        for (int v = 0; v < 3; ++v) {
            dv[v] = snapz((((Av[3 * v] * nbx) + (Av[3 * v + 1] * nby)) + (Av[3 * v + 2] * nbz)) + db);
            du[v] = snapz((((Bv[3 * v] * nax) + (Bv[3 * v + 1] * nay)) + (Bv[3 * v + 2] * naz)) + da);
        }

        const bool ssv = (dv[0] > 0.0f && dv[1] > 0.0f && dv[2] > 0.0f) ||
                         (dv[0] < 0.0f && dv[1] < 0.0f && dv[2] < 0.0f);
        const bool ssu = (du[0] > 0.0f && du[1] > 0.0f && du[2] > 0.0f) ||
                         (du[0] < 0.0f && du[1] < 0.0f && du[2] < 0.0f);

        // Plane-plane line direction, dominant axis (first-occurrence argmax).
        const float Dx = nay * nbz - naz * nby;
        const float Dy = naz * nbx - nax * nbz;
        const float Dz = nax * nby - nay * nbx;
        const float m0 = fabsf(Dx), m1 = fabsf(Dy), m2 = fabsf(Dz);
        int axm = 0;
        float mm = m0;
        if (m1 > mm) { axm = 1; mm = m1; }
        if (m2 > mm) { axm = 2; }

        float pv[3], pu[3];
#pragma unroll
        for (int v = 0; v < 3; ++v) {
            pv[v] = (axm == 0) ? Av[3 * v] : ((axm == 1) ? Av[3 * v + 1] : Av[3 * v + 2]);
            pu[v] = (axm == 0) ? Bv[3 * v] : ((axm == 1) ? Bv[3 * v + 1] : Bv[3 * v + 2]);
        }

        float t0v, t1v, t0u, t1u;
        tri_interval(pv, dv, t0v, t1v);
        tri_interval(pu, du, t0u, t1u);

        const bool overlap = fmaxf(t0v, t0u) <= fminf(t1v, t1u);
        const bool hit = (!ssv) && (!ssu) && overlap;

        float res = hit ? 1.0f : 0.0f;
        if (i == j) res = 1.0f;
        Sres[r][tx] = res;
    }

    __syncthreads();

    // Coalesced float4 writes of the tile and (if off-diagonal) its mirror.
    {
        const int row = t >> 3;          // 0..31
        const int c4 = (t & 7) * 4;      // 0,4,...,28
        float4 v;
        v.x = Sres[row][c4 + 0]; v.y = Sres[row][c4 + 1];
        v.z = Sres[row][c4 + 2]; v.w = Sres[row][c4 + 3];
        *(float4*)&out[(size_t)(R + row) * n + C + c4] = v;
        if (tr != tc) {
            float4 w;
            w.x = Sres[c4 + 0][row]; w.y = Sres[c4 + 1][row];
            w.z = Sres[c4 + 2][row]; w.w = Sres[c4 + 3][row];
            *(float4*)&out[(size_t)(C + row) * n + R + c4] = w;
        }
    }
}

extern "C" void kernel_launch(void* const* d_in, const int* in_sizes, int n_in,
                              void* d_out, int out_size, void* d_ws, size_t ws_size,
                              hipStream_t stream) {
    const float* tri = (const float*)d_in[0];
    float* out = (float*)d_out;
    const int n = in_sizes[0] / 9;  // 2048
    float4* planes = (float4*)d_ws;

    plane_kernel<<<(n + 255) / 256, 256, 0, stream>>>(tri, planes, n);

    dim3 block(32, 8);
    dim3 grid(n / TS, n / TS);  // lower-tri blocks exit immediately
    tile_kernel<<<grid, block, 0, stream>>>(tri, planes, out, n);
}